// Round 1
// baseline (83.390 us; speedup 1.0000x reference)
//
#include <hip/hip_runtime.h>
#include <math.h>

// EntropyPatcher: B=256 rows, L=8192 tokens in [0,5), E=64.
// out = concat(blt_features[B,E], entropy[B,L]) as float32.
// Identity: blt = (sum_patches relu(mean*w1+b1) / P) @ w2^T + b2.
//
// One block of 1024 threads (16 waves) per row, 256 blocks = 1/CU.
// Entropy: register sliding window + 100-entry pair table (no v_log in hot path).
// Patch walk: per-chunk (128 tok) exit tables walked with masks in VGPRs,
// composed via packed-nibble function-composition shuffle scan.

constexpr int B_ = 256;
constexpr int L_ = 8192;
constexpr int E_ = 64;
constexpr int T_ = 1024;     // threads/block (16 waves)
constexpr int PT = 8;        // positions per thread
constexpr int CHUNK = 128;
constexpr int NCH = L_ / CHUNK;  // 64
constexpr int MAXPC = 44;        // ceil(128/3)=43 max patches/chunk (+1 pad)

__global__ __launch_bounds__(1024)
void entropy_patcher_kernel(const int* __restrict__ x,
                            const float* __restrict__ w1,
                            const float* __restrict__ b1,
                            const float* __restrict__ w2,
                            const float* __restrict__ b2,
                            float* __restrict__ dout) {
  __shared__ __align__(16) unsigned char tok8p[8 + L_ + 8];  // 0xFF sentinel pads
  __shared__ __align__(16) float csBuf[L_ + 4];              // cs[0..L]
  __shared__ __align__(16) float meanbuf[NCH][MAXPC];
  __shared__ __align__(16) float pairTab[100];               // f(a)+f(b), total=9
  __shared__ __align__(16) unsigned char maskBytes[T_];      // bit p: ent[p] > 1.5
  __shared__ unsigned char exitT[NCH][12];
  __shared__ float rcpTab[13];
  __shared__ int cntC[NCH];
  __shared__ int waveTot[16];
  __shared__ float Sred[16][E_];
  __shared__ float partG[16][E_];
  __shared__ float avgv[E_];
  __shared__ int PcountS;

  const int tid  = threadIdx.x;
  const int lane = tid & 63;
  const int wv   = tid >> 6;
  const int b    = blockIdx.x;

  const int* xr = x + b * L_;
  float* entOut = dout + (size_t)B_ * E_ + (size_t)b * L_;

  // ---------- Phase A: tokens -> LDS bytes; build tables ----------
  const int4 v0 = ((const int4*)xr)[2 * tid];
  const int4 v1 = ((const int4*)xr)[2 * tid + 1];
  unsigned pw0 = (unsigned)v0.x | ((unsigned)v0.y << 8) |
                 ((unsigned)v0.z << 16) | ((unsigned)v0.w << 24);
  unsigned pw1 = (unsigned)v1.x | ((unsigned)v1.y << 8) |
                 ((unsigned)v1.z << 16) | ((unsigned)v1.w << 24);
  *(uint2*)(tok8p + 8 + 8 * tid) = make_uint2(pw0, pw1);
  if (tid == 0) *(uint2*)(tok8p) = make_uint2(~0u, ~0u);
  if (tid == 1) *(uint2*)(tok8p + 8 + L_) = make_uint2(~0u, ~0u);
  if (tid < 100) {
    int a = tid / 10, c = tid - 10 * a;
    float pa = (float)a / 9.0f, pb = (float)c / 9.0f;
    float fa = -(pa * log2f(pa + 1e-12f));
    float fb = -(pb * log2f(pb + 1e-12f));
    pairTab[tid] = fa + fb;                      // f(0)=0 so f(e)=pairTab[10e]
  }
  if (tid >= 100 && tid < 113) {
    int n = tid - 100;
    rcpTab[n] = 1.0f / (float)(n == 0 ? 1 : n);
  }
  __syncthreads();

  // ---------- Phase B: sliding-window entropy, masks ----------
  // 24 token bytes covering global tokens 8t-8 .. 8t+15 (pads are 0xFF -> code 0)
  unsigned long long tw0 = *(const unsigned long long*)(tok8p + 8 * tid);
  unsigned long long tw1 = *(const unsigned long long*)(tok8p + 8 * tid + 8);
  unsigned long long tw2 = *(const unsigned long long*)(tok8p + 8 * tid + 16);
  unsigned code[20];                              // local idx l = g - (8t-8), use 4..19
  #pragma unroll
  for (int l = 4; l < 20; ++l) {
    unsigned byte = (l < 8)  ? (unsigned)((tw0 >> (8 * l)) & 0xff)
                  : (l < 16) ? (unsigned)((tw1 >> (8 * (l - 8))) & 0xff)
                             : (unsigned)((tw2 >> (8 * (l - 16))) & 0xff);
    code[l] = (byte <= 4u) ? (1u << (6 * byte)) : 0u;  // 5 counts in 6-bit fields
  }
  unsigned s = 0;
  #pragma unroll
  for (int l = 4; l <= 12; ++l) s += code[l];     // window of p = 8t
  float entv[PT];
  #pragma unroll
  for (int q = 0; q < PT; ++q) {
    if (q) s += code[q + 12] - code[q + 3];
    unsigned a  = s & 63u,        bb = (s >> 6) & 63u, cc = (s >> 12) & 63u;
    unsigned dd = (s >> 18) & 63u, ee = (s >> 24) & 63u;
    entv[q] = pairTab[a * 10u + bb] + pairTab[cc * 10u + dd] + pairTab[ee * 10u];
  }
  if (tid == 0 || tid == T_ - 1) {                // 8 clipped-window edge positions
    #pragma unroll
    for (int q = 0; q < PT; ++q) {
      int p = 8 * tid + q;
      if (p < 4 || p >= L_ - 4) {
        unsigned ss = 0;
        for (int l = q + 4; l <= q + 12; ++l) ss += code[l];
        unsigned cn[5] = { ss & 63u, (ss >> 6) & 63u, (ss >> 12) & 63u,
                           (ss >> 18) & 63u, (ss >> 24) & 63u };
        float rT = 1.0f / (float)(cn[0] + cn[1] + cn[2] + cn[3] + cn[4]);
        float ent = 0.f;
        for (int k2 = 0; k2 < 5; ++k2) {
          float pr = (float)cn[k2] * rT;
          ent -= pr * log2f(pr + 1e-12f);
        }
        entv[q] = ent;
      }
    }
  }
  ((float4*)entOut)[2 * tid]     = make_float4(entv[0], entv[1], entv[2], entv[3]);
  ((float4*)entOut)[2 * tid + 1] = make_float4(entv[4], entv[5], entv[6], entv[7]);
  unsigned mbyte = 0;
  #pragma unroll
  for (int q = 0; q < PT; ++q) mbyte |= (entv[q] > 1.5f ? 1u : 0u) << q;
  maskBytes[tid] = (unsigned char)mbyte;

  // ---------- Phase C: exclusive token prefix sums (exact ints in fp32) ----------
  int tk[8];
  #pragma unroll
  for (int j = 0; j < 4; ++j) {
    tk[j]     = (int)((pw0 >> (8 * j)) & 0xffu);
    tk[4 + j] = (int)((pw1 >> (8 * j)) & 0xffu);
  }
  int ls = tk[0] + tk[1] + tk[2] + tk[3] + tk[4] + tk[5] + tk[6] + tk[7];
  int incl = ls;
  #pragma unroll
  for (int d = 1; d < 64; d <<= 1) {
    int up = __shfl_up(incl, d, 64);
    if (lane >= d) incl += up;
  }
  if (lane == 63) waveTot[wv] = incl;
  __syncthreads();                                // publishes waveTot + maskBytes
  int base = 0;
  #pragma unroll
  for (int q = 0; q < 16; ++q) base += (q < wv) ? waveTot[q] : 0;
  float acc = (float)(base + incl - ls);
  {
    float4 c0, c1;
    c0.x = acc; acc += (float)tk[0]; c0.y = acc; acc += (float)tk[1];
    c0.z = acc; acc += (float)tk[2]; c0.w = acc; acc += (float)tk[3];
    c1.x = acc; acc += (float)tk[4]; c1.y = acc; acc += (float)tk[5];
    c1.z = acc; acc += (float)tk[6]; c1.w = acc; acc += (float)tk[7];
    ((float4*)csBuf)[2 * tid] = c0; ((float4*)csBuf)[2 * tid + 1] = c1;
    if (tid == T_ - 1) csBuf[L_] = acc;
  }

  // ---------- Phase D: per-(chunk, entry 0..11) exit walk, masks in VGPRs ----------
  unsigned long long m0 = 0, m1 = 0;
  if (tid < 768) {
    int c = tid & 63, o = tid >> 6;
    m0 = *(const unsigned long long*)(maskBytes + 16 * c);
    m1 = *(const unsigned long long*)(maskBytes + 16 * c + 8);
    int p = o;
    while (p < CHUNK) {
      unsigned long long mm = (p & 64) ? m1 : m0;
      p += ((mm >> (p & 63)) & 1ULL) ? 3 : 12;
    }
    exitT[c][o] = (unsigned char)(p - CHUNK);
  }
  __syncthreads();                                // exitT + csBuf ready

  // ---------- Compose exit maps (wave 0): packed 12x4-bit shuffle scan ----------
  int myOff = 0;
  if (tid < 64) {
    const unsigned* ep = (const unsigned*)&exitT[tid][0];  // stride 12 % 4 == 0
    unsigned u0 = ep[0], u1 = ep[1], u2 = ep[2];
    auto nib = [](unsigned w) {
      return (w & 0xFu) | ((w >> 4) & 0xF0u) | ((w >> 8) & 0xF00u) | ((w >> 12) & 0xF000u);
    };
    unsigned long long tab = (unsigned long long)nib(u0)
                           | ((unsigned long long)nib(u1) << 16)
                           | ((unsigned long long)nib(u2) << 32);
    #pragma unroll
    for (int d = 1; d < 64; d <<= 1) {
      unsigned long long other =
          (unsigned long long)__shfl_up((long long)tab, d, 64);
      if (lane >= d) {
        unsigned long long nt = 0;
        #pragma unroll
        for (int e = 0; e < 12; ++e) {
          unsigned oe  = (unsigned)((other >> (4 * e)) & 15ULL);
          unsigned val = (unsigned)((tab >> (4 * oe)) & 15ULL);
          nt |= (unsigned long long)val << (4 * e);
        }
        tab = nt;
      }
    }
    unsigned long long prev = (unsigned long long)__shfl_up((long long)tab, 1, 64);
    myOff = (lane == 0) ? 0 : (int)(prev & 15ULL);

    // ---------- Phase E: walk own chunk, emit patch means ----------
    int c = tid;
    int p = CHUNK * c + myOff;
    const int end = CHUNK * c + CHUNK;
    float csp = csBuf[p];
    int n = 0;
    while (p < end) {
      int lp = p - CHUNK * c;
      unsigned long long mm = (lp & 64) ? m1 : m0;
      int ps = ((mm >> (lp & 63)) & 1ULL) ? 3 : 12;
      int j = p + ps; if (j > L_) j = L_;
      float csj = csBuf[j];
      meanbuf[c][n++] = (csj - csp) * rcpTab[j - p];
      csp = csj; p = j;
    }
    cntC[c] = n;
    int tot = n;
    #pragma unroll
    for (int d2 = 32; d2; d2 >>= 1) tot += __shfl_xor(tot, d2, 64);
    if (lane == 0) PcountS = tot;
  }
  __syncthreads();

  // ---------- Phase F: S[e] = sum relu(mean*w1[e]+b1[e]) over patches ----------
  {
    const float w1v = w1[lane];
    const float b1v = b1[lane];
    float S = 0.0f;
    for (int c = wv; c < NCH; c += 16) {
      int n = cntC[c];
      const float* mb = &meanbuf[c][0];
      int j = 0;
      for (; j + 4 <= n; j += 4) {
        float4 m4 = *((const float4*)(mb + j));   // broadcast b128 read
        S += fmaxf(fmaf(m4.x, w1v, b1v), 0.0f);
        S += fmaxf(fmaf(m4.y, w1v, b1v), 0.0f);
        S += fmaxf(fmaf(m4.z, w1v, b1v), 0.0f);
        S += fmaxf(fmaf(m4.w, w1v, b1v), 0.0f);
      }
      for (; j < n; ++j) S += fmaxf(fmaf(mb[j], w1v, b1v), 0.0f);
    }
    Sred[wv][lane] = S;
  }
  __syncthreads();
  if (tid < 64) {
    float sm = 0.f;
    #pragma unroll
    for (int q = 0; q < 16; ++q) sm += Sred[q][tid];
    avgv[tid] = sm / (float)PcountS;
  }
  __syncthreads();

  // ---------- Phase G: tiny matvec out = avg @ w2^T + b2 ----------
  {
    float acc2 = 0.f;
    #pragma unroll
    for (int kk = 0; kk < 4; ++kk) {
      int k = 4 * wv + kk;
      acc2 = fmaf(avgv[k], w2[lane * 64 + k], acc2);
    }
    partG[wv][lane] = acc2;
  }
  __syncthreads();
  if (tid < 64) {
    float r = b2[tid];
    #pragma unroll
    for (int q = 0; q < 16; ++q) r += partG[q][tid];
    dout[(size_t)b * E_ + tid] = r;
  }
}

extern "C" void kernel_launch(void* const* d_in, const int* in_sizes, int n_in,
                              void* d_out, int out_size, void* d_ws, size_t ws_size,
                              hipStream_t stream) {
  const int*   x  = (const int*)d_in[0];
  const float* w1 = (const float*)d_in[1];
  const float* b1 = (const float*)d_in[2];
  const float* w2 = (const float*)d_in[3];
  const float* b2 = (const float*)d_in[4];
  float* out = (float*)d_out;
  entropy_patcher_kernel<<<B_, T_, 0, stream>>>(x, w1, b1, w2, b2, out);
}

// Round 7
// 82.289 us; speedup vs baseline: 1.0134x; 1.0134x over previous
//
#include <hip/hip_runtime.h>
#include <math.h>

// EntropyPatcher: B=256 rows, L=8192 tokens in [0,5), E=64.
// out = concat(blt_features[B,E], entropy[B,L]) as float32.
// Identity: blt = (sum_patches relu(mean*w1+b1) / P) @ w2^T + b2.
//
// One block of 1024 threads (16 waves) per row, 256 blocks = 1/CU.
// Entropy: register sliding window + 1000-entry TRIPLE table (2 LDS gathers
// per position instead of 3; no v_log in any hot path, edges table-ized).
// Patch walk: per-chunk (128 tok) exit tables walked with masks in VGPRs,
// composed via packed-nibble function-composition shuffle scan.

constexpr int B_ = 256;
constexpr int L_ = 8192;
constexpr int E_ = 64;
constexpr int T_ = 1024;     // threads/block (16 waves)
constexpr int PT = 8;        // positions per thread
constexpr int CHUNK = 128;
constexpr int NCH = L_ / CHUNK;  // 64
constexpr int MAXPC = 44;        // ceil(128/3)=43 max patches/chunk (+1 pad)

__global__ __launch_bounds__(1024)
void entropy_patcher_kernel(const int* __restrict__ x,
                            const float* __restrict__ w1,
                            const float* __restrict__ b1,
                            const float* __restrict__ w2,
                            const float* __restrict__ b2,
                            float* __restrict__ dout) {
  __shared__ __align__(16) unsigned char tok8p[8 + L_ + 8];  // 0xFF sentinel pads
  __shared__ __align__(16) float csBuf[L_ + 4];              // cs[0..L]
  __shared__ __align__(16) float meanbuf[NCH][MAXPC];
  __shared__ __align__(16) float tripleTab[1000];            // f(a)+f(b)+f(c), total=9
  __shared__ __align__(16) unsigned char maskBytes[T_];      // bit p: ent[p] > 1.5
  __shared__ unsigned char exitT[NCH][12];
  __shared__ float rcpTab[13];
  __shared__ float hTab[10];                                 // c*log2(c)
  __shared__ float l2Tab[13];                                // log2(n)
  __shared__ int cntC[NCH];
  __shared__ int waveTot[16];
  __shared__ float Sred[16][E_];
  __shared__ float partG[16][E_];
  __shared__ float avgv[E_];
  __shared__ int PcountS;

  const int tid  = threadIdx.x;
  const int lane = tid & 63;
  const int wv   = tid >> 6;
  const int b    = blockIdx.x;

  const int* xr = x + b * L_;
  float* entOut = dout + (size_t)B_ * E_ + (size_t)b * L_;

  // ---------- Phase A: tokens -> LDS bytes; build tables ----------
  const int4 v0 = ((const int4*)xr)[2 * tid];
  const int4 v1 = ((const int4*)xr)[2 * tid + 1];
  unsigned pw0 = (unsigned)v0.x | ((unsigned)v0.y << 8) |
                 ((unsigned)v0.z << 16) | ((unsigned)v0.w << 24);
  unsigned pw1 = (unsigned)v1.x | ((unsigned)v1.y << 8) |
                 ((unsigned)v1.z << 16) | ((unsigned)v1.w << 24);
  *(uint2*)(tok8p + 8 + 8 * tid) = make_uint2(pw0, pw1);
  if (tid == 0) *(uint2*)(tok8p) = make_uint2(~0u, ~0u);
  if (tid == 1) *(uint2*)(tok8p + 8 + L_) = make_uint2(~0u, ~0u);
  if (tid < 1000) {
    int a = tid / 100;
    int r = tid - 100 * a;
    int bq = r / 10, cq = r - 10 * bq;
    float pa = (float)a / 9.0f, pb = (float)bq / 9.0f, pc = (float)cq / 9.0f;
    float fa = -(pa * log2f(pa + 1e-12f));
    float fb = -(pb * log2f(pb + 1e-12f));
    float fc = -(pc * log2f(pc + 1e-12f));
    tripleTab[tid] = fa + fb + fc;               // f(0)=0 so pair = tripleTab[10*(d*10+e)]
  }
  if (tid >= 1000 && tid < 1010) {
    int n = tid - 1000;
    hTab[n] = (n > 0) ? (float)n * log2f((float)n) : 0.0f;
  }
  if (tid >= 1000 && tid < 1013) {
    int n = tid - 1000;
    rcpTab[n] = 1.0f / (float)(n == 0 ? 1 : n);
  }
  if (tid >= 1010 && tid < 1023) {
    int n = tid - 1010;
    l2Tab[n] = (n > 0) ? log2f((float)n) : 0.0f;
  }
  __syncthreads();

  // ---------- Phase B: sliding-window entropy, masks ----------
  // 24 token bytes covering global tokens 8t-8 .. 8t+15 (pads are 0xFF -> code 0)
  unsigned long long tw0 = *(const unsigned long long*)(tok8p + 8 * tid);
  unsigned long long tw1 = *(const unsigned long long*)(tok8p + 8 * tid + 8);
  unsigned long long tw2 = *(const unsigned long long*)(tok8p + 8 * tid + 16);
  unsigned code[20];                              // local idx l = g - (8t-8), use 4..19
  #pragma unroll
  for (int l = 4; l < 20; ++l) {
    unsigned byte = (l < 8)  ? (unsigned)((tw0 >> (8 * l)) & 0xff)
                  : (l < 16) ? (unsigned)((tw1 >> (8 * (l - 8))) & 0xff)
                             : (unsigned)((tw2 >> (8 * (l - 16))) & 0xff);
    code[l] = (byte <= 4u) ? (1u << (6 * byte)) : 0u;  // 5 counts in 6-bit fields
  }
  unsigned s = 0;
  #pragma unroll
  for (int l = 4; l <= 12; ++l) s += code[l];     // window of p = 8t
  float entv[PT];
  #pragma unroll
  for (int q = 0; q < PT; ++q) {
    if (q) s += code[q + 12] - code[q + 3];
    unsigned a  = s & 63u,        bb = (s >> 6) & 63u, cc = (s >> 12) & 63u;
    unsigned dd = (s >> 18) & 63u, ee = (s >> 24) & 63u;
    unsigned i1 = a * 100u + bb * 10u + cc;
    unsigned i2 = dd * 100u + ee * 10u;           // f(d)+f(e)+f(0)
    entv[q] = tripleTab[i1] + tripleTab[i2];
  }
  if (tid == 0 || tid == T_ - 1) {                // 8 clipped-window edge positions
    #pragma unroll
    for (int q = 0; q < PT; ++q) {
      int p = 8 * tid + q;
      if (p < 4 || p >= L_ - 4) {
        unsigned ss = 0;
        for (int l = q + 4; l <= q + 12; ++l) ss += code[l];
        unsigned cn[5] = { ss & 63u, (ss >> 6) & 63u, (ss >> 12) & 63u,
                           (ss >> 18) & 63u, (ss >> 24) & 63u };
        int tsum = (int)(cn[0] + cn[1] + cn[2] + cn[3] + cn[4]);
        float sh = hTab[cn[0]] + hTab[cn[1]] + hTab[cn[2]] + hTab[cn[3]] + hTab[cn[4]];
        entv[q] = l2Tab[tsum] - rcpTab[tsum] * sh;   // log2(t) - (1/t) * sum c*log2(c)
      }
    }
  }
  ((float4*)entOut)[2 * tid]     = make_float4(entv[0], entv[1], entv[2], entv[3]);
  ((float4*)entOut)[2 * tid + 1] = make_float4(entv[4], entv[5], entv[6], entv[7]);
  unsigned mbyte = 0;
  #pragma unroll
  for (int q = 0; q < PT; ++q) mbyte |= (entv[q] > 1.5f ? 1u : 0u) << q;
  maskBytes[tid] = (unsigned char)mbyte;

  // ---------- Phase C: exclusive token prefix sums (exact ints in fp32) ----------
  int tk[8];
  #pragma unroll
  for (int j = 0; j < 4; ++j) {
    tk[j]     = (int)((pw0 >> (8 * j)) & 0xffu);
    tk[4 + j] = (int)((pw1 >> (8 * j)) & 0xffu);
  }
  int ls = tk[0] + tk[1] + tk[2] + tk[3] + tk[4] + tk[5] + tk[6] + tk[7];
  int incl = ls;
  #pragma unroll
  for (int d = 1; d < 64; d <<= 1) {
    int up = __shfl_up(incl, d, 64);
    if (lane >= d) incl += up;
  }
  if (lane == 63) waveTot[wv] = incl;
  __syncthreads();                                // publishes waveTot + maskBytes
  int base = 0;
  #pragma unroll
  for (int q = 0; q < 16; ++q) base += (q < wv) ? waveTot[q] : 0;
  float acc = (float)(base + incl - ls);
  {
    float4 c0, c1;
    c0.x = acc; acc += (float)tk[0]; c0.y = acc; acc += (float)tk[1];
    c0.z = acc; acc += (float)tk[2]; c0.w = acc; acc += (float)tk[3];
    c1.x = acc; acc += (float)tk[4]; c1.y = acc; acc += (float)tk[5];
    c1.z = acc; acc += (float)tk[6]; c1.w = acc; acc += (float)tk[7];
    ((float4*)csBuf)[2 * tid] = c0; ((float4*)csBuf)[2 * tid + 1] = c1;
    if (tid == T_ - 1) csBuf[L_] = acc;
  }

  // ---------- Phase D: per-(chunk, entry 0..11) exit walk, masks in VGPRs ----------
  unsigned long long m0 = 0, m1 = 0;
  if (tid < 768) {
    int c = tid & 63, o = tid >> 6;
    m0 = *(const unsigned long long*)(maskBytes + 16 * c);
    m1 = *(const unsigned long long*)(maskBytes + 16 * c + 8);
    int p = o;
    while (p < CHUNK) {
      unsigned long long mm = (p & 64) ? m1 : m0;
      p += ((mm >> (p & 63)) & 1ULL) ? 3 : 12;
    }
    exitT[c][o] = (unsigned char)(p - CHUNK);
  }
  __syncthreads();                                // exitT + csBuf ready

  // ---------- Compose exit maps (wave 0): packed 12x4-bit shuffle scan ----------
  int myOff = 0;
  if (tid < 64) {
    const unsigned* ep = (const unsigned*)&exitT[tid][0];  // stride 12 % 4 == 0
    unsigned u0 = ep[0], u1 = ep[1], u2 = ep[2];
    auto nib = [](unsigned w) {
      return (w & 0xFu) | ((w >> 4) & 0xF0u) | ((w >> 8) & 0xF00u) | ((w >> 12) & 0xF000u);
    };
    unsigned long long tab = (unsigned long long)nib(u0)
                           | ((unsigned long long)nib(u1) << 16)
                           | ((unsigned long long)nib(u2) << 32);
    #pragma unroll
    for (int d = 1; d < 64; d <<= 1) {
      unsigned long long other =
          (unsigned long long)__shfl_up((long long)tab, d, 64);
      if (lane >= d) {
        unsigned long long nt = 0;
        #pragma unroll
        for (int e = 0; e < 12; ++e) {
          unsigned oe  = (unsigned)((other >> (4 * e)) & 15ULL);
          unsigned val = (unsigned)((tab >> (4 * oe)) & 15ULL);
          nt |= (unsigned long long)val << (4 * e);
        }
        tab = nt;
      }
    }
    unsigned long long prev = (unsigned long long)__shfl_up((long long)tab, 1, 64);
    myOff = (lane == 0) ? 0 : (int)(prev & 15ULL);

    // ---------- Phase E: walk own chunk, emit patch means ----------
    int c = tid;
    int p = CHUNK * c + myOff;
    const int end = CHUNK * c + CHUNK;
    float csp = csBuf[p];
    int n = 0;
    while (p < end) {
      int lp = p - CHUNK * c;
      unsigned long long mm = (lp & 64) ? m1 : m0;
      int ps = ((mm >> (lp & 63)) & 1ULL) ? 3 : 12;
      int j = p + ps; if (j > L_) j = L_;
      float csj = csBuf[j];
      meanbuf[c][n++] = (csj - csp) * rcpTab[j - p];
      csp = csj; p = j;
    }
    cntC[c] = n;
    int tot = n;
    #pragma unroll
    for (int d2 = 32; d2; d2 >>= 1) tot += __shfl_xor(tot, d2, 64);
    if (lane == 0) PcountS = tot;
  }
  __syncthreads();

  // ---------- Phase F: S[e] = sum relu(mean*w1[e]+b1[e]) over patches ----------
  {
    const float w1v = w1[lane];
    const float b1v = b1[lane];
    float S = 0.0f;
    for (int c = wv; c < NCH; c += 16) {
      int n = cntC[c];
      const float* mb = &meanbuf[c][0];
      int j = 0;
      for (; j + 4 <= n; j += 4) {
        float4 m4 = *((const float4*)(mb + j));   // broadcast b128 read
        S += fmaxf(fmaf(m4.x, w1v, b1v), 0.0f);
        S += fmaxf(fmaf(m4.y, w1v, b1v), 0.0f);
        S += fmaxf(fmaf(m4.z, w1v, b1v), 0.0f);
        S += fmaxf(fmaf(m4.w, w1v, b1v), 0.0f);
      }
      for (; j < n; ++j) S += fmaxf(fmaf(mb[j], w1v, b1v), 0.0f);
    }
    Sred[wv][lane] = S;
  }
  __syncthreads();
  if (tid < 64) {
    float sm = 0.f;
    #pragma unroll
    for (int q = 0; q < 16; ++q) sm += Sred[q][tid];
    avgv[tid] = sm / (float)PcountS;
  }
  __syncthreads();

  // ---------- Phase G: tiny matvec out = avg @ w2^T + b2 ----------
  {
    float acc2 = 0.f;
    #pragma unroll
    for (int kk = 0; kk < 4; ++kk) {
      int k = 4 * wv + kk;
      acc2 = fmaf(avgv[k], w2[lane * 64 + k], acc2);
    }
    partG[wv][lane] = acc2;
  }
  __syncthreads();
  if (tid < 64) {
    float r = b2[tid];
    #pragma unroll
    for (int q = 0; q < 16; ++q) r += partG[q][tid];
    dout[(size_t)b * E_ + tid] = r;
  }
}

extern "C" void kernel_launch(void* const* d_in, const int* in_sizes, int n_in,
                              void* d_out, int out_size, void* d_ws, size_t ws_size,
                              hipStream_t stream) {
  const int*   x  = (const int*)d_in[0];
  const float* w1 = (const float*)d_in[1];
  const float* b1 = (const float*)d_in[2];
  const float* w2 = (const float*)d_in[3];
  const float* b2 = (const float*)d_in[4];
  float* out = (float*)d_out;
  entropy_patcher_kernel<<<B_, T_, 0, stream>>>(x, w1, b1, w2, b2, out);
}

// Round 8
// 82.224 us; speedup vs baseline: 1.0142x; 1.0008x over previous
//
#include <hip/hip_runtime.h>
#include <math.h>

// EntropyPatcher: B=256 rows, L=8192 tokens in [0,5), E=64.
// out = concat(blt_features[B,E], entropy[B,L]) as float32.
// Identity: blt = (sum_patches relu(mean*w1+b1) / P) @ w2^T + b2.
//
// One block of 1024 threads (16 waves) per row, 256 blocks = 1/CU.
// Entropy: register sliding window + 1000-entry TRIPLE table (2 LDS gathers
// per position; no v_log in any hot path, edges table-ized).
// Patch walk: per-chunk (128 tok) exit tables + patch-START BITMASKS built in
// Phase D; composed via packed-nibble shuffle scan; means then filled by ALL
// 16 waves in parallel via popcount compaction (no serial wave-0 walk).

constexpr int B_ = 256;
constexpr int L_ = 8192;
constexpr int E_ = 64;
constexpr int T_ = 1024;     // threads/block (16 waves)
constexpr int PT = 8;        // positions per thread
constexpr int CHUNK = 128;
constexpr int NCH = L_ / CHUNK;  // 64
constexpr int MAXPC = 44;        // ceil(128/3)=43 max patches/chunk (+1 pad)

__global__ __launch_bounds__(1024)
void entropy_patcher_kernel(const int* __restrict__ x,
                            const float* __restrict__ w1,
                            const float* __restrict__ b1,
                            const float* __restrict__ w2,
                            const float* __restrict__ b2,
                            float* __restrict__ dout) {
  __shared__ __align__(16) unsigned char tok8p[8 + L_ + 8];  // 0xFF sentinel pads
  __shared__ __align__(16) float csBuf[L_ + 4];              // cs[0..L]
  __shared__ __align__(16) float meanbuf[NCH][MAXPC];
  __shared__ __align__(16) float tripleTab[1000];            // f(a)+f(b)+f(c), total=9
  __shared__ __align__(16) unsigned char maskBytes[T_];      // bit p: ent[p] > 1.5
  __shared__ __align__(16) unsigned long long startT[12][64][2]; // patch-start bits
  __shared__ unsigned char exitT[NCH][12];
  __shared__ unsigned char chosenOff[NCH];
  __shared__ float rcpTab[13];
  __shared__ float hTab[10];                                 // c*log2(c)
  __shared__ float l2Tab[13];                                // log2(n)
  __shared__ int cntC[NCH];
  __shared__ int waveTot[16];
  __shared__ float Sred[16][E_];
  __shared__ float partG[16][E_];
  __shared__ float avgv[E_];
  __shared__ int PcountS;

  const int tid  = threadIdx.x;
  const int lane = tid & 63;
  const int wv   = tid >> 6;
  const int b    = blockIdx.x;

  const int* xr = x + b * L_;
  float* entOut = dout + (size_t)B_ * E_ + (size_t)b * L_;

  // ---------- Phase A: tokens -> LDS bytes; build tables ----------
  const int4 v0 = ((const int4*)xr)[2 * tid];
  const int4 v1 = ((const int4*)xr)[2 * tid + 1];
  unsigned pw0 = (unsigned)v0.x | ((unsigned)v0.y << 8) |
                 ((unsigned)v0.z << 16) | ((unsigned)v0.w << 24);
  unsigned pw1 = (unsigned)v1.x | ((unsigned)v1.y << 8) |
                 ((unsigned)v1.z << 16) | ((unsigned)v1.w << 24);
  *(uint2*)(tok8p + 8 + 8 * tid) = make_uint2(pw0, pw1);
  if (tid == 0) *(uint2*)(tok8p) = make_uint2(~0u, ~0u);
  if (tid == 1) *(uint2*)(tok8p + 8 + L_) = make_uint2(~0u, ~0u);
  if (tid < 1000) {
    int a = tid / 100;
    int r = tid - 100 * a;
    int bq = r / 10, cq = r - 10 * bq;
    float pa = (float)a / 9.0f, pb = (float)bq / 9.0f, pc = (float)cq / 9.0f;
    float fa = -(pa * log2f(pa + 1e-12f));
    float fb = -(pb * log2f(pb + 1e-12f));
    float fc = -(pc * log2f(pc + 1e-12f));
    tripleTab[tid] = fa + fb + fc;               // f(0)=0 so pair = tripleTab[10*(d*10+e)]
  }
  if (tid >= 1000 && tid < 1010) {
    int n = tid - 1000;
    hTab[n] = (n > 0) ? (float)n * log2f((float)n) : 0.0f;
  }
  if (tid >= 1000 && tid < 1013) {
    int n = tid - 1000;
    rcpTab[n] = 1.0f / (float)(n == 0 ? 1 : n);
  }
  if (tid >= 1010 && tid < 1023) {
    int n = tid - 1010;
    l2Tab[n] = (n > 0) ? log2f((float)n) : 0.0f;
  }
  __syncthreads();

  // ---------- Phase B: sliding-window entropy, masks ----------
  // 24 token bytes covering global tokens 8t-8 .. 8t+15 (pads are 0xFF -> code 0)
  unsigned long long tw0 = *(const unsigned long long*)(tok8p + 8 * tid);
  unsigned long long tw1 = *(const unsigned long long*)(tok8p + 8 * tid + 8);
  unsigned long long tw2 = *(const unsigned long long*)(tok8p + 8 * tid + 16);
  unsigned code[20];                              // local idx l = g - (8t-8), use 4..19
  #pragma unroll
  for (int l = 4; l < 20; ++l) {
    unsigned byte = (l < 8)  ? (unsigned)((tw0 >> (8 * l)) & 0xff)
                  : (l < 16) ? (unsigned)((tw1 >> (8 * (l - 8))) & 0xff)
                             : (unsigned)((tw2 >> (8 * (l - 16))) & 0xff);
    code[l] = (byte <= 4u) ? (1u << (6 * byte)) : 0u;  // 5 counts in 6-bit fields
  }
  unsigned s = 0;
  #pragma unroll
  for (int l = 4; l <= 12; ++l) s += code[l];     // window of p = 8t
  float entv[PT];
  #pragma unroll
  for (int q = 0; q < PT; ++q) {
    if (q) s += code[q + 12] - code[q + 3];
    unsigned a  = s & 63u,        bb = (s >> 6) & 63u, cc = (s >> 12) & 63u;
    unsigned dd = (s >> 18) & 63u, ee = (s >> 24) & 63u;
    unsigned i1 = a * 100u + bb * 10u + cc;
    unsigned i2 = dd * 100u + ee * 10u;           // f(d)+f(e)+f(0)
    entv[q] = tripleTab[i1] + tripleTab[i2];
  }
  if (tid == 0 || tid == T_ - 1) {                // 8 clipped-window edge positions
    #pragma unroll
    for (int q = 0; q < PT; ++q) {
      int p = 8 * tid + q;
      if (p < 4 || p >= L_ - 4) {
        unsigned ss = 0;
        for (int l = q + 4; l <= q + 12; ++l) ss += code[l];
        unsigned cn[5] = { ss & 63u, (ss >> 6) & 63u, (ss >> 12) & 63u,
                           (ss >> 18) & 63u, (ss >> 24) & 63u };
        int tsum = (int)(cn[0] + cn[1] + cn[2] + cn[3] + cn[4]);
        float sh = hTab[cn[0]] + hTab[cn[1]] + hTab[cn[2]] + hTab[cn[3]] + hTab[cn[4]];
        entv[q] = l2Tab[tsum] - rcpTab[tsum] * sh;   // log2(t) - (1/t) * sum c*log2(c)
      }
    }
  }
  ((float4*)entOut)[2 * tid]     = make_float4(entv[0], entv[1], entv[2], entv[3]);
  ((float4*)entOut)[2 * tid + 1] = make_float4(entv[4], entv[5], entv[6], entv[7]);
  unsigned mbyte = 0;
  #pragma unroll
  for (int q = 0; q < PT; ++q) mbyte |= (entv[q] > 1.5f ? 1u : 0u) << q;
  maskBytes[tid] = (unsigned char)mbyte;

  // ---------- Phase C: exclusive token prefix sums (exact ints in fp32) ----------
  int tk[8];
  #pragma unroll
  for (int j = 0; j < 4; ++j) {
    tk[j]     = (int)((pw0 >> (8 * j)) & 0xffu);
    tk[4 + j] = (int)((pw1 >> (8 * j)) & 0xffu);
  }
  int ls = tk[0] + tk[1] + tk[2] + tk[3] + tk[4] + tk[5] + tk[6] + tk[7];
  int incl = ls;
  #pragma unroll
  for (int d = 1; d < 64; d <<= 1) {
    int up = __shfl_up(incl, d, 64);
    if (lane >= d) incl += up;
  }
  if (lane == 63) waveTot[wv] = incl;
  __syncthreads();                                // publishes waveTot + maskBytes
  int base = 0;
  #pragma unroll
  for (int q = 0; q < 16; ++q) base += (q < wv) ? waveTot[q] : 0;
  float acc = (float)(base + incl - ls);
  {
    float4 c0, c1;
    c0.x = acc; acc += (float)tk[0]; c0.y = acc; acc += (float)tk[1];
    c0.z = acc; acc += (float)tk[2]; c0.w = acc; acc += (float)tk[3];
    c1.x = acc; acc += (float)tk[4]; c1.y = acc; acc += (float)tk[5];
    c1.z = acc; acc += (float)tk[6]; c1.w = acc; acc += (float)tk[7];
    ((float4*)csBuf)[2 * tid] = c0; ((float4*)csBuf)[2 * tid + 1] = c1;
    if (tid == T_ - 1) csBuf[L_] = acc;
  }

  // ---------- Phase D: per-(chunk, entry 0..11) exit walk + start bitmask ----------
  if (tid < 768) {
    int c = tid & 63, o = tid >> 6;
    unsigned long long m0 = *(const unsigned long long*)(maskBytes + 16 * c);
    unsigned long long m1 = *(const unsigned long long*)(maskBytes + 16 * c + 8);
    unsigned long long sA = 0, sB = 0;
    int p = o;
    while (p < CHUNK) {
      if (p < 64) sA |= 1ull << p; else sB |= 1ull << (p - 64);
      unsigned long long mm = (p & 64) ? m1 : m0;
      p += ((mm >> (p & 63)) & 1ULL) ? 3 : 12;
    }
    exitT[c][o] = (unsigned char)(p - CHUNK);
    startT[o][c][0] = sA;
    startT[o][c][1] = sB;
  }
  __syncthreads();                                // exitT + startT + csBuf ready

  // ---------- Compose exit maps (wave 0): packed 12x4-bit shuffle scan ----------
  if (tid < 64) {
    const unsigned* ep = (const unsigned*)&exitT[tid][0];  // stride 12 % 4 == 0
    unsigned u0 = ep[0], u1 = ep[1], u2 = ep[2];
    auto nib = [](unsigned w) {
      return (w & 0xFu) | ((w >> 4) & 0xF0u) | ((w >> 8) & 0xF00u) | ((w >> 12) & 0xF000u);
    };
    unsigned long long tab = (unsigned long long)nib(u0)
                           | ((unsigned long long)nib(u1) << 16)
                           | ((unsigned long long)nib(u2) << 32);
    #pragma unroll
    for (int d = 1; d < 64; d <<= 1) {
      unsigned long long other =
          (unsigned long long)__shfl_up((long long)tab, d, 64);
      if (lane >= d) {
        unsigned long long nt = 0;
        #pragma unroll
        for (int e = 0; e < 12; ++e) {
          unsigned oe  = (unsigned)((other >> (4 * e)) & 15ULL);
          unsigned val = (unsigned)((tab >> (4 * oe)) & 15ULL);
          nt |= (unsigned long long)val << (4 * e);
        }
        tab = nt;
      }
    }
    unsigned long long prev = (unsigned long long)__shfl_up((long long)tab, 1, 64);
    int myOff = (lane == 0) ? 0 : (int)(prev & 15ULL);
    chosenOff[tid] = (unsigned char)myOff;
    // patch count via popcount of the chosen start masks (no walk)
    unsigned long long sA = startT[myOff][tid][0];
    unsigned long long sB = startT[myOff][tid][1];
    int tot = __popcll(sA) + __popcll(sB);
    #pragma unroll
    for (int d2 = 32; d2; d2 >>= 1) tot += __shfl_xor(tot, d2, 64);
    if (lane == 0) PcountS = tot;
  }
  __syncthreads();                                // chosenOff ready

  // ---------- Phase E': parallel mean fill (all 16 waves, popcount compaction) ----------
  for (int c = wv; c < NCH; c += 16) {
    int off = chosenOff[c];                                      // broadcast
    unsigned long long smA = startT[off][c][0];                  // broadcast
    unsigned long long smB = startT[off][c][1];                  // broadcast
    unsigned long long mmA = *(const unsigned long long*)(maskBytes + 16 * c);
    unsigned long long mmB = *(const unsigned long long*)(maskBytes + 16 * c + 8);
    int pc0 = __popcll(smA);
    #pragma unroll
    for (int t = 0; t < 2; ++t) {
      int lp = 2 * lane + t;
      unsigned long long smw = (lp < 64) ? smA : smB;
      unsigned long long mmw = (lp < 64) ? mmA : mmB;
      int bi = lp & 63;
      if ((smw >> bi) & 1ULL) {
        int p = CHUNK * c + lp;
        int ps = ((mmw >> bi) & 1ULL) ? 3 : 12;
        int j = p + ps; if (j > L_) j = L_;
        unsigned long long below = smw & ((1ull << bi) - 1ull);
        int n = __popcll(below) + ((lp < 64) ? 0 : pc0);
        meanbuf[c][n] = (csBuf[j] - csBuf[p]) * rcpTab[j - p];
      }
    }
    if (lane == 0) cntC[c] = pc0 + __popcll(smB);
  }
  __syncthreads();

  // ---------- Phase F: S[e] = sum relu(mean*w1[e]+b1[e]) over patches ----------
  {
    const float w1v = w1[lane];
    const float b1v = b1[lane];
    float S = 0.0f;
    for (int c = wv; c < NCH; c += 16) {
      int n = cntC[c];
      const float* mb = &meanbuf[c][0];
      int j = 0;
      for (; j + 4 <= n; j += 4) {
        float4 m4 = *((const float4*)(mb + j));   // broadcast b128 read
        S += fmaxf(fmaf(m4.x, w1v, b1v), 0.0f);
        S += fmaxf(fmaf(m4.y, w1v, b1v), 0.0f);
        S += fmaxf(fmaf(m4.z, w1v, b1v), 0.0f);
        S += fmaxf(fmaf(m4.w, w1v, b1v), 0.0f);
      }
      for (; j < n; ++j) S += fmaxf(fmaf(mb[j], w1v, b1v), 0.0f);
    }
    Sred[wv][lane] = S;
  }
  __syncthreads();
  if (tid < 64) {
    float sm = 0.f;
    #pragma unroll
    for (int q = 0; q < 16; ++q) sm += Sred[q][tid];
    avgv[tid] = sm / (float)PcountS;
  }
  __syncthreads();

  // ---------- Phase G: tiny matvec out = avg @ w2^T + b2 ----------
  {
    float acc2 = 0.f;
    #pragma unroll
    for (int kk = 0; kk < 4; ++kk) {
      int k = 4 * wv + kk;
      acc2 = fmaf(avgv[k], w2[lane * 64 + k], acc2);
    }
    partG[wv][lane] = acc2;
  }
  __syncthreads();
  if (tid < 64) {
    float r = b2[tid];
    #pragma unroll
    for (int q = 0; q < 16; ++q) r += partG[q][tid];
    dout[(size_t)b * E_ + tid] = r;
  }
}

extern "C" void kernel_launch(void* const* d_in, const int* in_sizes, int n_in,
                              void* d_out, int out_size, void* d_ws, size_t ws_size,
                              hipStream_t stream) {
  const int*   x  = (const int*)d_in[0];
  const float* w1 = (const float*)d_in[1];
  const float* b1 = (const float*)d_in[2];
  const float* w2 = (const float*)d_in[3];
  const float* b2 = (const float*)d_in[4];
  float* out = (float*)d_out;
  entropy_patcher_kernel<<<B_, T_, 0, stream>>>(x, w1, b1, w2, b2, out);
}